// Round 1
// baseline (1730.737 us; speedup 1.0000x reference)
//
#include <hip/hip_runtime.h>

typedef float f2v __attribute__((ext_vector_type(2)));

__device__ __forceinline__ float fetch_tap(const float* __restrict__ t, int W, int H, int x, int y) {
    bool valid = ((unsigned)x < (unsigned)W) & ((unsigned)y < (unsigned)H);
    int xc = min(max(x, 0), W - 1);
    int yc = min(max(y, 0), H - 1);
    float v = t[(size_t)yc * (size_t)W + (size_t)xc];
    return valid ? v : 0.0f;
}

__device__ __forceinline__ float sample_layer(const float* __restrict__ t, int W, int H,
                                              float gx, float gy) {
    // Match reference op order exactly (fp32):
    float ix = ((gx + 1.0f) * (float)W - 1.0f) * 0.5f;
    float iy = ((gy + 1.0f) * (float)H - 1.0f) * 0.5f;
    float x0f = floorf(ix), y0f = floorf(iy);
    float wx1 = ix - x0f, wy1 = iy - y0f;
    float wx0 = 1.0f - wx1, wy0 = 1.0f - wy1;
    int x0 = (int)x0f, y0 = (int)y0f;
    float v00 = fetch_tap(t, W, H, x0,     y0);
    float v10 = fetch_tap(t, W, H, x0 + 1, y0);
    float v01 = fetch_tap(t, W, H, x0,     y0 + 1);
    float v11 = fetch_tap(t, W, H, x0 + 1, y0 + 1);
    return (v00 * wx0 + v10 * wx1) * wy0 + (v01 * wx0 + v11 * wx1) * wy1;
}

__global__ __launch_bounds__(256) void texture_sample_kernel(
        const f2v* __restrict__ x,
        const float* __restrict__ l1,
        const float* __restrict__ l2,
        const float* __restrict__ l3,
        const float* __restrict__ l4,
        float* __restrict__ out, int n) {
    int i = blockIdx.x * blockDim.x + threadIdx.x;
    if (i >= n) return;

    // Streamed once: non-temporal load keeps textures resident in L2/L3.
    f2v g = __builtin_nontemporal_load(x + i);
    float gx = g.x * 2.0f - 1.0f;
    float gy = g.y * 2.0f - 1.0f;

    float acc;
    acc  = sample_layer(l1, 4096, 4096, gx, gy);
    acc += sample_layer(l2, 2048, 2048, gx, gy);
    acc += sample_layer(l3, 1024, 1024, gx, gy);
    acc += sample_layer(l4,  512,  512, gx, gy);

    __builtin_nontemporal_store(acc, out + i);
}

extern "C" void kernel_launch(void* const* d_in, const int* in_sizes, int n_in,
                              void* d_out, int out_size, void* d_ws, size_t ws_size,
                              hipStream_t stream) {
    const f2v*  x  = (const f2v*)d_in[0];
    const float* l1 = (const float*)d_in[1];
    const float* l2 = (const float*)d_in[2];
    const float* l3 = (const float*)d_in[3];
    const float* l4 = (const float*)d_in[4];
    float* out = (float*)d_out;

    int n = out_size;  // 4096*4096 pixels
    int block = 256;
    int grid = (n + block - 1) / block;
    texture_sample_kernel<<<grid, block, 0, stream>>>(x, l1, l2, l3, l4, out, n);
}

// Round 2
// 1048.935 us; speedup vs baseline: 1.6500x; 1.6500x over previous
//
#include <hip/hip_runtime.h>

typedef float f2v __attribute__((ext_vector_type(2)));
typedef unsigned short u16x8 __attribute__((ext_vector_type(8)));

// ---------- bf16 helpers (RNE) ----------
__device__ __forceinline__ unsigned short f2bf(float f) {
    unsigned u = __float_as_uint(f);
    unsigned r = (u + 0x7FFFu + ((u >> 16) & 1u)) >> 16;
    return (unsigned short)r;
}
__device__ __forceinline__ float bf2f(unsigned short h) {
    return __uint_as_float(((unsigned)h) << 16);
}

// ---------- tiled layout: tile = 8 wide x 4 tall = 32 bf16 texels = 64 B ----------
__device__ __forceinline__ int tiled_off(int W, int x, int y) {
    // element offset (ushort units)
    return (((y >> 2) * (W >> 3) + (x >> 3)) << 5) + ((y & 3) << 3) + (x & 7);
}

__global__ __launch_bounds__(256) void convert_tiled(const float* __restrict__ src,
                                                     unsigned short* __restrict__ dst,
                                                     int W, int total /* (W>>3)*H */) {
    int t = blockIdx.x * blockDim.x + threadIdx.x;
    if (t >= total) return;
    int wp = W >> 3;
    int y = t / wp;
    int xg = (t - y * wp) << 3;
    const float4* s = (const float4*)(src + (size_t)y * W + xg);
    float4 a = s[0], b = s[1];
    u16x8 r;
    r[0] = f2bf(a.x); r[1] = f2bf(a.y); r[2] = f2bf(a.z); r[3] = f2bf(a.w);
    r[4] = f2bf(b.x); r[5] = f2bf(b.y); r[6] = f2bf(b.z); r[7] = f2bf(b.w);
    *(u16x8*)(dst + tiled_off(W, xg, y)) = r;
}

// ---------- bilinear sample from tiled bf16 ----------
template <int W, int H>
__device__ __forceinline__ float sample_layer_t(const unsigned short* __restrict__ t,
                                                float gx, float gy) {
    float ix = ((gx + 1.0f) * (float)W - 1.0f) * 0.5f;
    float iy = ((gy + 1.0f) * (float)H - 1.0f) * 0.5f;
    float x0f = floorf(ix), y0f = floorf(iy);
    float wx1 = ix - x0f, wy1 = iy - y0f;
    float wx0 = 1.0f - wx1, wy0 = 1.0f - wy1;
    int x0 = (int)x0f, y0 = (int)y0f;
    int x1 = x0 + 1, y1 = y0 + 1;
    bool vx0 = (unsigned)x0 < (unsigned)W, vx1 = (unsigned)x1 < (unsigned)W;
    bool vy0 = (unsigned)y0 < (unsigned)H, vy1 = (unsigned)y1 < (unsigned)H;
    int cx0 = min(max(x0, 0), W - 1), cx1 = min(max(x1, 0), W - 1);
    int cy0 = min(max(y0, 0), H - 1), cy1 = min(max(y1, 0), H - 1);
    float v00 = bf2f(t[tiled_off(W, cx0, cy0)]); v00 = (vx0 & vy0) ? v00 : 0.0f;
    float v10 = bf2f(t[tiled_off(W, cx1, cy0)]); v10 = (vx1 & vy0) ? v10 : 0.0f;
    float v01 = bf2f(t[tiled_off(W, cx0, cy1)]); v01 = (vx0 & vy1) ? v01 : 0.0f;
    float v11 = bf2f(t[tiled_off(W, cx1, cy1)]); v11 = (vx1 & vy1) ? v11 : 0.0f;
    return v00 * (wx0 * wy0) + v10 * (wx1 * wy0) + v01 * (wx0 * wy1) + v11 * (wx1 * wy1);
}

__global__ __launch_bounds__(256) void texture_sample_tiled(
        const f2v* __restrict__ x,
        const unsigned short* __restrict__ l1,
        const unsigned short* __restrict__ l2,
        const unsigned short* __restrict__ l3,
        const unsigned short* __restrict__ l4,
        float* __restrict__ out, int n) {
    int i = blockIdx.x * blockDim.x + threadIdx.x;
    if (i >= n) return;
    f2v g = __builtin_nontemporal_load(x + i);
    float gx = g.x * 2.0f - 1.0f;
    float gy = g.y * 2.0f - 1.0f;
    float acc;
    acc  = sample_layer_t<4096, 4096>(l1, gx, gy);
    acc += sample_layer_t<2048, 2048>(l2, gx, gy);
    acc += sample_layer_t<1024, 1024>(l3, gx, gy);
    acc += sample_layer_t< 512,  512>(l4, gx, gy);
    __builtin_nontemporal_store(acc, out + i);
}

// ---------- fallback: direct fp32 path (used only if ws too small) ----------
__device__ __forceinline__ float fetch_tap(const float* __restrict__ t, int W, int H, int x, int y) {
    bool valid = ((unsigned)x < (unsigned)W) & ((unsigned)y < (unsigned)H);
    int xc = min(max(x, 0), W - 1);
    int yc = min(max(y, 0), H - 1);
    float v = t[(size_t)yc * (size_t)W + (size_t)xc];
    return valid ? v : 0.0f;
}
__device__ __forceinline__ float sample_layer(const float* __restrict__ t, int W, int H,
                                              float gx, float gy) {
    float ix = ((gx + 1.0f) * (float)W - 1.0f) * 0.5f;
    float iy = ((gy + 1.0f) * (float)H - 1.0f) * 0.5f;
    float x0f = floorf(ix), y0f = floorf(iy);
    float wx1 = ix - x0f, wy1 = iy - y0f;
    float wx0 = 1.0f - wx1, wy0 = 1.0f - wy1;
    int x0 = (int)x0f, y0 = (int)y0f;
    float v00 = fetch_tap(t, W, H, x0,     y0);
    float v10 = fetch_tap(t, W, H, x0 + 1, y0);
    float v01 = fetch_tap(t, W, H, x0,     y0 + 1);
    float v11 = fetch_tap(t, W, H, x0 + 1, y0 + 1);
    return (v00 * wx0 + v10 * wx1) * wy0 + (v01 * wx0 + v11 * wx1) * wy1;
}
__global__ __launch_bounds__(256) void texture_sample_direct(
        const f2v* __restrict__ x,
        const float* __restrict__ l1, const float* __restrict__ l2,
        const float* __restrict__ l3, const float* __restrict__ l4,
        float* __restrict__ out, int n) {
    int i = blockIdx.x * blockDim.x + threadIdx.x;
    if (i >= n) return;
    f2v g = __builtin_nontemporal_load(x + i);
    float gx = g.x * 2.0f - 1.0f;
    float gy = g.y * 2.0f - 1.0f;
    float acc;
    acc  = sample_layer(l1, 4096, 4096, gx, gy);
    acc += sample_layer(l2, 2048, 2048, gx, gy);
    acc += sample_layer(l3, 1024, 1024, gx, gy);
    acc += sample_layer(l4,  512,  512, gx, gy);
    __builtin_nontemporal_store(acc, out + i);
}

extern "C" void kernel_launch(void* const* d_in, const int* in_sizes, int n_in,
                              void* d_out, int out_size, void* d_ws, size_t ws_size,
                              hipStream_t stream) {
    const f2v*   x  = (const f2v*)d_in[0];
    const float* l1 = (const float*)d_in[1];
    const float* l2 = (const float*)d_in[2];
    const float* l3 = (const float*)d_in[3];
    const float* l4 = (const float*)d_in[4];
    float* out = (float*)d_out;
    int n = out_size;                       // 4096*4096
    int block = 256;
    int grid = (n + block - 1) / block;

    // ws layout: l1t 32MB | l2t 8MB | l3t 2MB | l4t 0.5MB
    const size_t OFF1 = 0;
    const size_t OFF2 = (size_t)4096 * 4096 * 2;            // 32 MB
    const size_t OFF3 = OFF2 + (size_t)2048 * 2048 * 2;     // +8 MB
    const size_t OFF4 = OFF3 + (size_t)1024 * 1024 * 2;     // +2 MB
    const size_t NEED = OFF4 + (size_t)512 * 512 * 2;       // 42.5 MB total

    if (ws_size >= NEED) {
        unsigned short* t1 = (unsigned short*)((char*)d_ws + OFF1);
        unsigned short* t2 = (unsigned short*)((char*)d_ws + OFF2);
        unsigned short* t3 = (unsigned short*)((char*)d_ws + OFF3);
        unsigned short* t4 = (unsigned short*)((char*)d_ws + OFF4);

        int g1 = (4096 / 8) * 4096, g2 = (2048 / 8) * 2048;
        int g3 = (1024 / 8) * 1024, g4 = (512 / 8) * 512;
        convert_tiled<<<(g1 + 255) / 256, 256, 0, stream>>>(l1, t1, 4096, g1);
        convert_tiled<<<(g2 + 255) / 256, 256, 0, stream>>>(l2, t2, 2048, g2);
        convert_tiled<<<(g3 + 255) / 256, 256, 0, stream>>>(l3, t3, 1024, g3);
        convert_tiled<<<(g4 + 255) / 256, 256, 0, stream>>>(l4, t4,  512, g4);

        texture_sample_tiled<<<grid, block, 0, stream>>>(x, t1, t2, t3, t4, out, n);
    } else {
        texture_sample_direct<<<grid, block, 0, stream>>>(x, l1, l2, l3, l4, out, n);
    }
}